// Round 2
// baseline (863.871 us; speedup 1.0000x reference)
//
#include <hip/hip_runtime.h>
#include <hip/hip_bf16.h>

typedef __bf16 bf16;
typedef bf16 bf16x8 __attribute__((ext_vector_type(8)));
typedef float f32x4 __attribute__((ext_vector_type(4)));
typedef unsigned short u16;

#define B_ 4
#define S_ 2048
#define D_ 1024
#define H_ 16
#define HD_ 64

#define NEG_SENT -30000.0f

// workspace layout (bf16 element offsets)
#define XN_OFF   ((size_t)0)          // 8388608 elems; reused as Ab after QKV
#define WT_OFF   ((size_t)8388608)    // 4 x 1048576
#define BN_OFF   ((size_t)12582912)   // 4 x 1024
#define FLAG_BYTE ((size_t)25174016)  // int flag
#define Q_OFF    ((size_t)12587520)
#define K_OFF    ((size_t)20976128)
#define VT_OFF   ((size_t)29364736)

union Pack4 { bf16 b[4]; uint2 q; };
union U4V  { uint4 u; bf16x8 v; };

__device__ __forceinline__ void load16(const bf16* g, bf16* l) {
    __builtin_amdgcn_global_load_lds(
        (const __attribute__((address_space(1))) void*)g,
        (__attribute__((address_space(3))) void*)l, 16, 0, 0);
}

// ---------------- dtype detection ----------------
__global__ __launch_bounds__(256) void detect_k(const u16* __restrict__ x,
                                                int* __restrict__ flag)
{
    __shared__ int cnt;
    if (threadIdx.x == 0) cnt = 0;
    __syncthreads();
    int c = 0;
    for (int i = threadIdx.x; i < 4096; i += 256) {
        u16 w = x[i * 2];            // even-indexed words
        int e = (w >> 7) & 0xFF;
        if (e >= 100 && e <= 135) c++;
    }
    atomicAdd(&cnt, c);
    __syncthreads();
    if (threadIdx.x == 0) *flag = (cnt > 2048) ? 1 : 0;   // 1 = bf16
}

// ---------------- input normalization: x -> bf16 XN ----------------
__global__ __launch_bounds__(256) void norm_x_k(const void* __restrict__ src,
                                                bf16* __restrict__ dst,
                                                const int* __restrict__ flag)
{
    const int qi = blockIdx.x * 256 + threadIdx.x;   // quad index, 4 elems each
    if (*flag) {
        ((uint2*)dst)[qi] = ((const uint2*)src)[qi];
    } else {
        float4 v = ((const float4*)src)[qi];
        Pack4 p;
        p.b[0] = (bf16)v.x; p.b[1] = (bf16)v.y;
        p.b[2] = (bf16)v.z; p.b[3] = (bf16)v.w;
        ((uint2*)dst)[qi] = p.q;
    }
}

// ---------------- bias normalization ----------------
__global__ __launch_bounds__(256) void norm_b_k(
    const void* __restrict__ b0, const void* __restrict__ b1,
    const void* __restrict__ b2, const void* __restrict__ b3,
    bf16* __restrict__ BN, const int* __restrict__ flag)
{
    const int mat = blockIdx.x;
    const void* src = (mat == 0) ? b0 : (mat == 1) ? b1 : (mat == 2) ? b2 : b3;
    bf16* dst = BN + mat * 1024;
    const int i = threadIdx.x * 4;
    if (*flag) {
        ((uint2*)(dst + i))[0] = *(const uint2*)((const bf16*)src + i);
    } else {
        const float* s = (const float*)src;
        Pack4 p;
        p.b[0] = (bf16)s[i + 0]; p.b[1] = (bf16)s[i + 1];
        p.b[2] = (bf16)s[i + 2]; p.b[3] = (bf16)s[i + 3];
        ((uint2*)(dst + i))[0] = p.q;
    }
}

// ---------- weight normalize + transpose: W[K][N] -> WT[N][K] (bf16) ----------
__global__ __launch_bounds__(256) void transpose_w(
    const void* __restrict__ W0, const void* __restrict__ W1,
    const void* __restrict__ W2, const void* __restrict__ W3,
    bf16* __restrict__ WT, const int* __restrict__ flag)
{
    __shared__ __align__(16) bf16 tile[64][65];
    const int mat = blockIdx.z;
    const void* W = (mat == 0) ? W0 : (mat == 1) ? W1 : (mat == 2) ? W2 : W3;
    bf16* O = WT + ((size_t)mat << 20);
    const int r0 = blockIdx.y * 64, c0 = blockIdx.x * 64;
    const int t = threadIdx.x;
    const int isb = *flag;
    #pragma unroll
    for (int i = 0; i < 16; ++i) {
        int idx = t + i * 256;
        int r = idx >> 6, c = idx & 63;
        size_t off = (size_t)(r0 + r) * D_ + c0 + c;
        tile[r][c] = isb ? ((const bf16*)W)[off] : (bf16)((const float*)W)[off];
    }
    __syncthreads();
    #pragma unroll
    for (int i = 0; i < 16; ++i) {
        int idx = t + i * 256;
        int rr = idx & 63, cc = idx >> 6;
        O[(size_t)(c0 + cc) * D_ + r0 + rr] = tile[rr][cc];
    }
}

// ---------------- shared 128x128 GEMM mainloop (m97 structure) ----------------
__device__ __forceinline__ void gemm_core(const bf16* __restrict__ A,
                                          const bf16* __restrict__ Bt,
                                          bf16* lA, bf16* lB,
                                          f32x4 acc[4][4], int m0, int n0)
{
    const int t = threadIdx.x;
    const int lane = t & 63;
    const int wave = t >> 6;
    const int wm = (wave >> 1) << 6;
    const int wn = (wave & 1) << 6;
    const int quad = lane >> 4;
    const int col = lane & 15;
    for (int k0 = 0; k0 < D_; k0 += 32) {
        #pragma unroll
        for (int i = 0; i < 2; ++i) {
            int slot = t + i * 256;
            int row = slot >> 2;
            int kc = (slot & 3) << 3;
            load16(A + (size_t)(m0 + row) * D_ + k0 + kc, lA + slot * 8);
            load16(Bt + (size_t)(n0 + row) * D_ + k0 + kc, lB + slot * 8);
        }
        __syncthreads();
        bf16x8 af[4], bfr[4];
        #pragma unroll
        for (int mi = 0; mi < 4; ++mi)
            af[mi] = *(const bf16x8*)(lA + (wm + mi * 16 + col) * 32 + quad * 8);
        #pragma unroll
        for (int ni = 0; ni < 4; ++ni)
            bfr[ni] = *(const bf16x8*)(lB + (wn + ni * 16 + col) * 32 + quad * 8);
        #pragma unroll
        for (int mi = 0; mi < 4; ++mi)
            #pragma unroll
            for (int ni = 0; ni < 4; ++ni)
                acc[mi][ni] = __builtin_amdgcn_mfma_f32_16x16x32_bf16(
                    af[mi], bfr[ni], acc[mi][ni], 0, 0, 0);
        __syncthreads();
    }
}

// ---------------- QKV projection ----------------
// mode 0: Q scaled by (1/8)*log2(e) -> [b][h][s][hd]; mode 1: K; mode 2: V^T
__global__ __launch_bounds__(256) void gemm_qkv_k(
    const bf16* __restrict__ X, const bf16* __restrict__ WT,
    const bf16* __restrict__ BN,
    bf16* __restrict__ Qo, bf16* __restrict__ Ko, bf16* __restrict__ Vo)
{
    __shared__ __align__(16) bf16 lA[128 * 32];
    __shared__ __align__(16) bf16 lB[128 * 32];
    const int mode = blockIdx.z;
    const bf16* Wsel = WT + ((size_t)mode << 20);
    const bf16* bias = BN + mode * 1024;
    f32x4 acc[4][4];
    const f32x4 z = {0.f, 0.f, 0.f, 0.f};
    #pragma unroll
    for (int i = 0; i < 4; ++i)
        #pragma unroll
        for (int j = 0; j < 4; ++j) acc[i][j] = z;
    const int m0 = blockIdx.x * 128, n0 = blockIdx.y * 128;
    gemm_core(X, Wsel, lA, lB, acc, m0, n0);
    const int t = threadIdx.x, lane = t & 63, wave = t >> 6;
    const int wm = (wave >> 1) << 6, wn = (wave & 1) << 6;
    const int quad = lane >> 4, col = lane & 15;
    // 0.125 * log2(e): softmax later uses raw exp2
    const float scale = (mode == 0) ? 0.18033688011112042f : 1.0f;
    #pragma unroll
    for (int mi = 0; mi < 4; ++mi) {
        int gm = m0 + wm + mi * 16 + quad * 4;
        int b = gm >> 11, srow = gm & 2047;
        #pragma unroll
        for (int ni = 0; ni < 4; ++ni) {
            int gn = n0 + wn + ni * 16 + col;
            float bb = (float)bias[gn];
            int h = gn >> 6, hd = gn & 63;
            if (mode == 2) {
                // V^T: 4 r-values are contiguous in s -> one 8B store
                Pack4 pk;
                #pragma unroll
                for (int r = 0; r < 4; ++r)
                    pk.b[r] = (bf16)(acc[mi][ni][r] + bb);
                *(uint2*)(Vo + (((size_t)b * H_ + h) * HD_ + hd) * S_ + srow)
                    = pk.q;
            } else {
                #pragma unroll
                for (int r = 0; r < 4; ++r) {
                    float v = (acc[mi][ni][r] + bb) * scale;
                    if (mode == 1)
                        Ko[(((size_t)b * H_ + h) * S_ + srow + r) * HD_ + hd] = (bf16)v;
                    else
                        Qo[(((size_t)b * H_ + h) * S_ + srow + r) * HD_ + hd] = (bf16)v;
                }
            }
        }
    }
}

__device__ __forceinline__ void tile_epilogue(
    bf16* __restrict__ Aout, int b, int h, int wq0,
    const f32x4 o[4], const f32x4& o4)
{
    const int lane = threadIdx.x & 63;
    const int quad = lane >> 4, col = lane & 15;
    // row-sum l(q) lives in o4[0] of lane (quad=0, col=q) -> broadcast
    float l = __shfl(o4[0], col);
    const float inv = 1.f / fmaxf(l, 1e-30f);
    const int qg = wq0 + col;
    #pragma unroll
    for (int dt = 0; dt < 4; ++dt) {
        Pack4 pk;
        #pragma unroll
        for (int r = 0; r < 4; ++r) pk.b[r] = (bf16)(o[dt][r] * inv);
        *(uint2*)(Aout + ((size_t)b * S_ + qg) * D_ + h * HD_
                  + dt * 16 + quad * 4) = pk.q;
    }
}

// ---------------- flash attention (causal) --------------------------------
// grid: (16, B*H). Block i runs q-tiles (31-i) [L] and (i) [S] in ONE k-loop
// over double-buffered K/V LDS tiles (issue-early staging: stage t+1 before
// computing t, single __syncthreads per iter whose vmcnt(0) lands after the
// compute phase has hidden the HBM latency).
//
// P never touches LDS: PV uses a k-permutation k(quad,j)=kk*32+(j>>2)*16+
// quad*4+(j&3) applied identically to the V^T A-fragment (two 8B LDS reads)
// and the P^T B-fragment, which then is exactly the lane's packed exp2(st)
// registers (bit-cast, zero cross-lane traffic). Row-sum l comes from a
// ones-row MFMA (permutation-invariant), so l matches the bf16 P exactly.
__global__ __launch_bounds__(256, 4) void attn_k(
    const bf16* __restrict__ Q, const bf16* __restrict__ K,
    const bf16* __restrict__ VT, bf16* __restrict__ Aout)
{
    __shared__ __align__(16) bf16 lK[2][64 * 64];   // [k][d], chunk^=(k&7)
    __shared__ __align__(16) bf16 lV[2][64 * 64];   // [d][k], chunk^=(d&7)
    const int bh = blockIdx.y;
    const bf16* Qp = Q + (size_t)bh * S_ * HD_;
    const bf16* Kp = K + (size_t)bh * S_ * HD_;
    const bf16* Vp = VT + (size_t)bh * HD_ * S_;
    const int b = bh >> 4, h = bh & 15;
    const int t = threadIdx.x;
    const int lane = t & 63, w = t >> 6;
    const int quad = lane >> 4, col = lane & 15;

    const int q0L = (31 - (int)blockIdx.x) * 64;
    const int q0S = (int)blockIdx.x * 64;
    const int wq0L = q0L + w * 16, wq0S = q0S + w * 16;
    const int nt = 32 - (int)blockIdx.x;          // staged k-tiles

    // Q fragments (B-operand): B[n=q][k=d], n=col, k=quad*8+j
    bf16x8 qfL[2], qfS[2];
    #pragma unroll
    for (int cc = 0; cc < 2; ++cc) {
        qfL[cc] = *(const bf16x8*)(Qp + (size_t)(wq0L + col) * HD_
                                   + cc * 32 + quad * 8);
        qfS[cc] = *(const bf16x8*)(Qp + (size_t)(wq0S + col) * HD_
                                   + cc * 32 + quad * 8);
    }
    // ones-row A-fragment for the MFMA row-sum: A[m][k] = (m==0)
    const bf16 ov = (bf16)(col == 0 ? 1.0f : 0.0f);
    const bf16x8 vf4 = {ov, ov, ov, ov, ov, ov, ov, ov};

    f32x4 oL[4], oS[4], o4L, o4S;
    const f32x4 z = {0.f, 0.f, 0.f, 0.f};
    #pragma unroll
    for (int dt = 0; dt < 4; ++dt) { oL[dt] = z; oS[dt] = z; }
    o4L = z; o4S = z;
    float mstL = NEG_SENT, mstS = NEG_SENT;

    // ---- stage K[k0:+64][0:64] and V^T[0:64][k0:+64] into buffer bb ----
    auto stage = [&](int k0, int bb) {
        #pragma unroll
        for (int i = 0; i < 2; ++i) {
            int slot = t + i * 256;          // 0..511
            int rr = slot >> 3, ch = slot & 7;
            int sw = (ch ^ (rr & 7)) << 3;
            load16(Kp + (size_t)(k0 + rr) * HD_ + sw, &lK[bb][slot * 8]);
            load16(Vp + (size_t)rr * S_ + k0 + sw, &lV[bb][slot * 8]);
        }
    };

    stage(0, 0);
    __syncthreads();
    int cur = 0;

    for (int it = 0; it < nt; ++it) {
        const int k0 = it << 6;
        if (it + 1 < nt) stage(k0 + 64, cur ^ 1);   // issue-early prefetch
        const bf16* K_ = &lK[cur][0];
        const bf16* V_ = &lV[cur][0];
        const bool doS = (k0 <= q0S);

        bool incL[4], incS[4];
        #pragma unroll
        for (int mt = 0; mt < 4; ++mt) {
            incL[mt] = (k0 + mt * 16 <= wq0L + 15);
            incS[mt] = (k0 + mt * 16 <= wq0S + 15);
        }

        // ---- QK^T for both tiles, sharing each K fragment read ----
        f32x4 stL[4], stS[4];
        #pragma unroll
        for (int mt = 0; mt < 4; ++mt) { stL[mt] = z; stS[mt] = z; }
        __builtin_amdgcn_s_setprio(1);
        #pragma unroll
        for (int cc = 0; cc < 2; ++cc) {
            #pragma unroll
            for (int mt = 0; mt < 4; ++mt) {
                if (incL[mt]) {
                    bf16x8 af = *(const bf16x8*)(K_ + (mt * 16 + col) * 64
                                + (((cc * 4 + quad) ^ (col & 7)) << 3));
                    stL[mt] = __builtin_amdgcn_mfma_f32_16x16x32_bf16(
                        af, qfL[cc], stL[mt], 0, 0, 0);
                    if (doS && incS[mt])
                        stS[mt] = __builtin_amdgcn_mfma_f32_16x16x32_bf16(
                            af, qfS[cc], stS[mt], 0, 0, 0);
                }
            }
        }
        __builtin_amdgcn_s_setprio(0);

        // ---- softmax L ----
        uint2 pkL[4], pkS[4];
        {
            if (k0 + 64 > wq0L) { // diagonal region: mask k > q
                #pragma unroll
                for (int mt = 0; mt < 4; ++mt)
                    if (incL[mt]) {
                        #pragma unroll
                        for (int r = 0; r < 4; ++r)
                            if (k0 + mt * 16 + quad * 4 + r > wq0L + col)
                                stL[mt][r] = NEG_SENT;
                    }
            }
            float tm = fmaxf(fmaxf(stL[0][0], stL[0][1]),
                             fmaxf(stL[0][2], stL[0][3]));
            #pragma unroll
            for (int mt = 1; mt < 4; ++mt)
                if (incL[mt])
                    tm = fmaxf(tm, fmaxf(fmaxf(stL[mt][0], stL[mt][1]),
                                         fmaxf(stL[mt][2], stL[mt][3])));
            tm = fmaxf(tm, __shfl_xor(tm, 16));
            tm = fmaxf(tm, __shfl_xor(tm, 32));
            if (!__all(tm <= mstL + 8.0f)) {   // deferred-max (T13)
                float mn = fmaxf(mstL, tm);
                float al = exp2f(mstL - mn);
                #pragma unroll
                for (int dt = 0; dt < 4; ++dt) oL[dt] *= al;
                o4L *= al;
                mstL = mn;
            }
            #pragma unroll
            for (int mt = 0; mt < 4; ++mt) {
                if (incL[mt]) {
                    Pack4 pk;
                    #pragma unroll
                    for (int r = 0; r < 4; ++r)
                        pk.b[r] = (bf16)exp2f(stL[mt][r] - mstL);
                    pkL[mt] = pk.q;
                } else {
                    pkL[mt].x = 0u; pkL[mt].y = 0u;
                }
            }
        }
        // ---- softmax S ----
        if (doS) {
            if (k0 + 64 > wq0S) {
                #pragma unroll
                for (int mt = 0; mt < 4; ++mt)
                    if (incS[mt]) {
                        #pragma unroll
                        for (int r = 0; r < 4; ++r)
                            if (k0 + mt * 16 + quad * 4 + r > wq0S + col)
                                stS[mt][r] = NEG_SENT;
                    }
            }
            float tm = fmaxf(fmaxf(stS[0][0], stS[0][1]),
                             fmaxf(stS[0][2], stS[0][3]));
            #pragma unroll
            for (int mt = 1; mt < 4; ++mt)
                if (incS[mt])
                    tm = fmaxf(tm, fmaxf(fmaxf(stS[mt][0], stS[mt][1]),
                                         fmaxf(stS[mt][2], stS[mt][3])));
            tm = fmaxf(tm, __shfl_xor(tm, 16));
            tm = fmaxf(tm, __shfl_xor(tm, 32));
            if (!__all(tm <= mstS + 8.0f)) {
                float mn = fmaxf(mstS, tm);
                float al = exp2f(mstS - mn);
                #pragma unroll
                for (int dt = 0; dt < 4; ++dt) oS[dt] *= al;
                o4S *= al;
                mstS = mn;
            }
            #pragma unroll
            for (int mt = 0; mt < 4; ++mt) {
                if (incS[mt]) {
                    Pack4 pk;
                    #pragma unroll
                    for (int r = 0; r < 4; ++r)
                        pk.b[r] = (bf16)exp2f(stS[mt][r] - mstS);
                    pkS[mt] = pk.q;
                } else {
                    pkS[mt].x = 0u; pkS[mt].y = 0u;
                }
            }
        }

        // ---- PV for both tiles: permuted-k V reads, in-register P ----
        __builtin_amdgcn_s_setprio(1);
        #pragma unroll
        for (int kk = 0; kk < 2; ++kk) {
            const bool needL = (kk == 0) ? true : incL[2];
            const bool needS = doS && ((kk == 0) ? true : incS[2]);
            if (!needL && !needS) continue;
            U4V fl, fs;
            fl.u.x = pkL[2 * kk].x;     fl.u.y = pkL[2 * kk].y;
            fl.u.z = pkL[2 * kk + 1].x; fl.u.w = pkL[2 * kk + 1].y;
            if (needS) {
                fs.u.x = pkS[2 * kk].x;     fs.u.y = pkS[2 * kk].y;
                fs.u.z = pkS[2 * kk + 1].x; fs.u.w = pkS[2 * kk + 1].y;
            }
            const int c0 = kk * 4 + (quad >> 1);
            const int co = (quad & 1) << 2;
            #pragma unroll
            for (int dt = 0; dt < 4; ++dt) {
                const bf16* vrow = V_ + (size_t)(dt * 16 + col) * 64;
                uint2 va = *(const uint2*)(vrow + ((c0 ^ (col & 7)) << 3) + co);
                uint2 vb = *(const uint2*)(vrow + (((c0 + 2) ^ (col & 7)) << 3) + co);
                U4V vv;
                vv.u.x = va.x; vv.u.y = va.y; vv.u.z = vb.x; vv.u.w = vb.y;
                if (needL)
                    oL[dt] = __builtin_amdgcn_mfma_f32_16x16x32_bf16(
                        vv.v, fl.v, oL[dt], 0, 0, 0);
                if (needS)
                    oS[dt] = __builtin_amdgcn_mfma_f32_16x16x32_bf16(
                        vv.v, fs.v, oS[dt], 0, 0, 0);
            }
            if (needL)
                o4L = __builtin_amdgcn_mfma_f32_16x16x32_bf16(
                    vf4, fl.v, o4L, 0, 0, 0);
            if (needS)
                o4S = __builtin_amdgcn_mfma_f32_16x16x32_bf16(
                    vf4, fs.v, o4S, 0, 0, 0);
        }
        __builtin_amdgcn_s_setprio(0);

        __syncthreads();   // drains prefetch vmcnt (hidden under compute)
        cur ^= 1;
    }

    tile_epilogue(Aout, b, h, wq0L, oL, o4L);
    tile_epilogue(Aout, b, h, wq0S, oS, o4S);
}

// ---------------- output projection (dtype-aware store) ----------------
__global__ __launch_bounds__(256) void gemm_out_k(
    const bf16* __restrict__ A, const bf16* __restrict__ WoT,
    const bf16* __restrict__ Bo, void* __restrict__ Out,
    const int* __restrict__ flag)
{
    __shared__ __align__(16) bf16 lA[128 * 32];
    __shared__ __align__(16) bf16 lB[128 * 32];
    f32x4 acc[4][4];
    const f32x4 z = {0.f, 0.f, 0.f, 0.f};
    #pragma unroll
    for (int i = 0; i < 4; ++i)
        #pragma unroll
        for (int j = 0; j < 4; ++j) acc[i][j] = z;
    const int m0 = blockIdx.x * 128, n0 = blockIdx.y * 128;
    gemm_core(A, WoT, lA, lB, acc, m0, n0);
    const int t = threadIdx.x, lane = t & 63, wave = t >> 6;
    const int wm = (wave >> 1) << 6, wn = (wave & 1) << 6;
    const int quad = lane >> 4, col = lane & 15;
    const int isb = *flag;
    #pragma unroll
    for (int mi = 0; mi < 4; ++mi) {
        int gm = m0 + wm + mi * 16 + quad * 4;
        #pragma unroll
        for (int ni = 0; ni < 4; ++ni) {
            int gn = n0 + wn + ni * 16 + col;
            float bb = (float)Bo[gn];
            #pragma unroll
            for (int r = 0; r < 4; ++r) {
                float v = acc[mi][ni][r] + bb;
                size_t off = (size_t)(gm + r) * D_ + gn;
                if (isb) ((bf16*)Out)[off] = (bf16)v;
                else     ((float*)Out)[off] = v;
            }
        }
    }
}

extern "C" void kernel_launch(void* const* d_in, const int* in_sizes, int n_in,
                              void* d_out, int out_size, void* d_ws, size_t ws_size,
                              hipStream_t stream)
{
    const void* x  = d_in[0];
    const void* wq = d_in[1];
    const void* bq = d_in[2];
    const void* wk = d_in[3];
    const void* bk = d_in[4];
    const void* wv = d_in[5];
    const void* bv = d_in[6];
    const void* wo = d_in[7];
    const void* bo = d_in[8];

    bf16* ws  = (bf16*)d_ws;
    bf16* XN  = ws + XN_OFF;                 // also reused as Ab
    bf16* WT  = ws + WT_OFF;
    bf16* BN  = ws + BN_OFF;
    int*  flag = (int*)((char*)d_ws + FLAG_BYTE);
    bf16* Qb  = ws + Q_OFF;
    bf16* Kb  = ws + K_OFF;
    bf16* VTb = ws + VT_OFF;
    bf16* Ab  = XN;

    hipLaunchKernelGGL(detect_k, dim3(1), dim3(256), 0, stream,
                       (const u16*)x, flag);
    hipLaunchKernelGGL(norm_x_k, dim3(8192), dim3(256), 0, stream,
                       x, XN, flag);
    hipLaunchKernelGGL(transpose_w, dim3(16, 16, 4), dim3(256), 0, stream,
                       wq, wk, wv, wo, WT, flag);
    hipLaunchKernelGGL(norm_b_k, dim3(4), dim3(256), 0, stream,
                       bq, bk, bv, bo, BN, flag);
    hipLaunchKernelGGL(gemm_qkv_k, dim3(64, 8, 3), dim3(256), 0, stream,
                       XN, WT, BN, Qb, Kb, VTb);
    hipLaunchKernelGGL(attn_k, dim3(16, 64), dim3(256), 0, stream,
                       Qb, Kb, VTb, Ab);
    hipLaunchKernelGGL(gemm_out_k, dim3(64, 8), dim3(256), 0, stream,
                       Ab, WT + ((size_t)3u << 20), BN + 3072, d_out, flag);
}

// Round 3
// 592.394 us; speedup vs baseline: 1.4583x; 1.4583x over previous
//
#include <hip/hip_runtime.h>
#include <hip/hip_bf16.h>

typedef __bf16 bf16;
typedef bf16 bf16x8 __attribute__((ext_vector_type(8)));
typedef float f32x4 __attribute__((ext_vector_type(4)));
typedef unsigned short u16;

#define B_ 4
#define S_ 2048
#define D_ 1024
#define H_ 16
#define HD_ 64

#define NEG_SENT -30000.0f

// workspace layout (bf16 element offsets)
#define XN_OFF   ((size_t)0)          // 8388608 elems; reused as Ab after QKV
#define WT_OFF   ((size_t)8388608)    // 4 x 1048576
#define BN_OFF   ((size_t)12582912)   // 4 x 1024
#define FLAG_BYTE ((size_t)25174016)  // int flag
#define Q_OFF    ((size_t)12587520)
#define K_OFF    ((size_t)20976128)
#define VT_OFF   ((size_t)29364736)

union Pack4 { bf16 b[4]; uint2 q; };
union U4V  { uint4 u; bf16x8 v; };

__device__ __forceinline__ void load16(const bf16* g, bf16* l) {
    __builtin_amdgcn_global_load_lds(
        (const __attribute__((address_space(1))) void*)g,
        (__attribute__((address_space(3))) void*)l, 16, 0, 0);
}

// ---------------- dtype detection ----------------
__global__ __launch_bounds__(256) void detect_k(const u16* __restrict__ x,
                                                int* __restrict__ flag)
{
    __shared__ int cnt;
    if (threadIdx.x == 0) cnt = 0;
    __syncthreads();
    int c = 0;
    for (int i = threadIdx.x; i < 4096; i += 256) {
        u16 w = x[i * 2];            // even-indexed words
        int e = (w >> 7) & 0xFF;
        if (e >= 100 && e <= 135) c++;
    }
    atomicAdd(&cnt, c);
    __syncthreads();
    if (threadIdx.x == 0) *flag = (cnt > 2048) ? 1 : 0;   // 1 = bf16
}

// ---------------- input normalization: x -> bf16 XN ----------------
__global__ __launch_bounds__(256) void norm_x_k(const void* __restrict__ src,
                                                bf16* __restrict__ dst,
                                                const int* __restrict__ flag)
{
    const int qi = blockIdx.x * 256 + threadIdx.x;   // quad index, 4 elems each
    if (*flag) {
        ((uint2*)dst)[qi] = ((const uint2*)src)[qi];
    } else {
        float4 v = ((const float4*)src)[qi];
        Pack4 p;
        p.b[0] = (bf16)v.x; p.b[1] = (bf16)v.y;
        p.b[2] = (bf16)v.z; p.b[3] = (bf16)v.w;
        ((uint2*)dst)[qi] = p.q;
    }
}

// ---------------- bias normalization ----------------
__global__ __launch_bounds__(256) void norm_b_k(
    const void* __restrict__ b0, const void* __restrict__ b1,
    const void* __restrict__ b2, const void* __restrict__ b3,
    bf16* __restrict__ BN, const int* __restrict__ flag)
{
    const int mat = blockIdx.x;
    const void* src = (mat == 0) ? b0 : (mat == 1) ? b1 : (mat == 2) ? b2 : b3;
    bf16* dst = BN + mat * 1024;
    const int i = threadIdx.x * 4;
    if (*flag) {
        ((uint2*)(dst + i))[0] = *(const uint2*)((const bf16*)src + i);
    } else {
        const float* s = (const float*)src;
        Pack4 p;
        p.b[0] = (bf16)s[i + 0]; p.b[1] = (bf16)s[i + 1];
        p.b[2] = (bf16)s[i + 2]; p.b[3] = (bf16)s[i + 3];
        ((uint2*)(dst + i))[0] = p.q;
    }
}

// ---------- weight normalize + transpose: W[K][N] -> WT[N][K] (bf16) ----------
__global__ __launch_bounds__(256) void transpose_w(
    const void* __restrict__ W0, const void* __restrict__ W1,
    const void* __restrict__ W2, const void* __restrict__ W3,
    bf16* __restrict__ WT, const int* __restrict__ flag)
{
    __shared__ __align__(16) bf16 tile[64][65];
    const int mat = blockIdx.z;
    const void* W = (mat == 0) ? W0 : (mat == 1) ? W1 : (mat == 2) ? W2 : W3;
    bf16* O = WT + ((size_t)mat << 20);
    const int r0 = blockIdx.y * 64, c0 = blockIdx.x * 64;
    const int t = threadIdx.x;
    const int isb = *flag;
    #pragma unroll
    for (int i = 0; i < 16; ++i) {
        int idx = t + i * 256;
        int r = idx >> 6, c = idx & 63;
        size_t off = (size_t)(r0 + r) * D_ + c0 + c;
        tile[r][c] = isb ? ((const bf16*)W)[off] : (bf16)((const float*)W)[off];
    }
    __syncthreads();
    #pragma unroll
    for (int i = 0; i < 16; ++i) {
        int idx = t + i * 256;
        int rr = idx & 63, cc = idx >> 6;
        O[(size_t)(c0 + cc) * D_ + r0 + rr] = tile[rr][cc];
    }
}

// ---------------- shared 128x128 GEMM mainloop (m97 structure) ----------------
__device__ __forceinline__ void gemm_core(const bf16* __restrict__ A,
                                          const bf16* __restrict__ Bt,
                                          bf16* lA, bf16* lB,
                                          f32x4 acc[4][4], int m0, int n0)
{
    const int t = threadIdx.x;
    const int lane = t & 63;
    const int wave = t >> 6;
    const int wm = (wave >> 1) << 6;
    const int wn = (wave & 1) << 6;
    const int quad = lane >> 4;
    const int col = lane & 15;
    for (int k0 = 0; k0 < D_; k0 += 32) {
        #pragma unroll
        for (int i = 0; i < 2; ++i) {
            int slot = t + i * 256;
            int row = slot >> 2;
            int kc = (slot & 3) << 3;
            load16(A + (size_t)(m0 + row) * D_ + k0 + kc, lA + slot * 8);
            load16(Bt + (size_t)(n0 + row) * D_ + k0 + kc, lB + slot * 8);
        }
        __syncthreads();
        bf16x8 af[4], bfr[4];
        #pragma unroll
        for (int mi = 0; mi < 4; ++mi)
            af[mi] = *(const bf16x8*)(lA + (wm + mi * 16 + col) * 32 + quad * 8);
        #pragma unroll
        for (int ni = 0; ni < 4; ++ni)
            bfr[ni] = *(const bf16x8*)(lB + (wn + ni * 16 + col) * 32 + quad * 8);
        #pragma unroll
        for (int mi = 0; mi < 4; ++mi)
            #pragma unroll
            for (int ni = 0; ni < 4; ++ni)
                acc[mi][ni] = __builtin_amdgcn_mfma_f32_16x16x32_bf16(
                    af[mi], bfr[ni], acc[mi][ni], 0, 0, 0);
        __syncthreads();
    }
}

// ---------------- QKV projection ----------------
// mode 0: Q scaled by (1/8)*log2(e) -> [b][h][s][hd]; mode 1: K; mode 2: V^T
__global__ __launch_bounds__(256) void gemm_qkv_k(
    const bf16* __restrict__ X, const bf16* __restrict__ WT,
    const bf16* __restrict__ BN,
    bf16* __restrict__ Qo, bf16* __restrict__ Ko, bf16* __restrict__ Vo)
{
    __shared__ __align__(16) bf16 lA[128 * 32];
    __shared__ __align__(16) bf16 lB[128 * 32];
    const int mode = blockIdx.z;
    const bf16* Wsel = WT + ((size_t)mode << 20);
    const bf16* bias = BN + mode * 1024;
    f32x4 acc[4][4];
    const f32x4 z = {0.f, 0.f, 0.f, 0.f};
    #pragma unroll
    for (int i = 0; i < 4; ++i)
        #pragma unroll
        for (int j = 0; j < 4; ++j) acc[i][j] = z;
    const int m0 = blockIdx.x * 128, n0 = blockIdx.y * 128;
    gemm_core(X, Wsel, lA, lB, acc, m0, n0);
    const int t = threadIdx.x, lane = t & 63, wave = t >> 6;
    const int wm = (wave >> 1) << 6, wn = (wave & 1) << 6;
    const int quad = lane >> 4, col = lane & 15;
    // 0.125 * log2(e): softmax later uses raw exp2
    const float scale = (mode == 0) ? 0.18033688011112042f : 1.0f;
    #pragma unroll
    for (int mi = 0; mi < 4; ++mi) {
        int gm = m0 + wm + mi * 16 + quad * 4;
        int b = gm >> 11, srow = gm & 2047;
        #pragma unroll
        for (int ni = 0; ni < 4; ++ni) {
            int gn = n0 + wn + ni * 16 + col;
            float bb = (float)bias[gn];
            int h = gn >> 6, hd = gn & 63;
            if (mode == 2) {
                // V^T: 4 r-values are contiguous in s -> one 8B store
                Pack4 pk;
                #pragma unroll
                for (int r = 0; r < 4; ++r)
                    pk.b[r] = (bf16)(acc[mi][ni][r] + bb);
                *(uint2*)(Vo + (((size_t)b * H_ + h) * HD_ + hd) * S_ + srow)
                    = pk.q;
            } else {
                #pragma unroll
                for (int r = 0; r < 4; ++r) {
                    float v = (acc[mi][ni][r] + bb) * scale;
                    if (mode == 1)
                        Ko[(((size_t)b * H_ + h) * S_ + srow + r) * HD_ + hd] = (bf16)v;
                    else
                        Qo[(((size_t)b * H_ + h) * S_ + srow + r) * HD_ + hd] = (bf16)v;
                }
            }
        }
    }
}

// ---- one 64-k step of one q-tile: QK^T -> online softmax (deferred max) ->
//      PV with in-register P (permuted-k; no LDS round-trip).
//      Sequential per tile to cap live registers (R2 lesson: interleaving
//      both q-tiles spilled ~32 dwords/thread/iter -> 2 GB scratch traffic).
__device__ __forceinline__ void tile_body(
    const bf16* __restrict__ K_, const bf16* __restrict__ V_,
    const bf16x8 qf[2], const bf16x8& vf4,
    f32x4 o[4], f32x4& o4, float& mst,
    int k0, int wq0)
{
    const int lane = threadIdx.x & 63;
    const int quad = lane >> 4, col = lane & 15;
    const f32x4 z = {0.f, 0.f, 0.f, 0.f};
    // wave-uniform tile inclusion (k-subtile mt needed iff its min k <= max q)
    bool inc[4];
    #pragma unroll
    for (int mt = 0; mt < 4; ++mt)
        inc[mt] = (k0 + mt * 16 <= wq0 + 15);

    // ---- S^T[mt=k] = K·Q^T ----
    f32x4 st[4];
    #pragma unroll
    for (int mt = 0; mt < 4; ++mt) st[mt] = z;
    __builtin_amdgcn_s_setprio(1);
    #pragma unroll
    for (int cc = 0; cc < 2; ++cc) {
        #pragma unroll
        for (int mt = 0; mt < 4; ++mt)
            if (inc[mt]) {
                bf16x8 af = *(const bf16x8*)(K_ + (mt * 16 + col) * 64
                            + (((cc * 4 + quad) ^ (col & 7)) << 3));
                st[mt] = __builtin_amdgcn_mfma_f32_16x16x32_bf16(
                    af, qf[cc], st[mt], 0, 0, 0);
            }
    }
    __builtin_amdgcn_s_setprio(0);

    // ---- diagonal mask ----
    if (k0 + 64 > wq0) {
        #pragma unroll
        for (int mt = 0; mt < 4; ++mt)
            if (inc[mt]) {
                #pragma unroll
                for (int r = 0; r < 4; ++r)
                    if (k0 + mt * 16 + quad * 4 + r > wq0 + col)
                        st[mt][r] = NEG_SENT;
            }
    }

    // ---- online max per q (= col) ----
    float tm = fmaxf(fmaxf(st[0][0], st[0][1]), fmaxf(st[0][2], st[0][3]));
    #pragma unroll
    for (int mt = 1; mt < 4; ++mt)
        if (inc[mt])
            tm = fmaxf(tm, fmaxf(fmaxf(st[mt][0], st[mt][1]),
                                 fmaxf(st[mt][2], st[mt][3])));
    tm = fmaxf(tm, __shfl_xor(tm, 16));
    tm = fmaxf(tm, __shfl_xor(tm, 32));
    // deferred-max (T13): only rescale when max grew by > 8 (exp2 units);
    // P then bounded by 2^8 = 256 — bf16-safe.
    if (!__all(tm <= mst + 8.0f)) {
        float mn = fmaxf(mst, tm);
        float al = exp2f(mst - mn);
        #pragma unroll
        for (int dt = 0; dt < 4; ++dt) o[dt] *= al;
        o4 *= al;
        mst = mn;
    }

    // ---- PV: per kk build P fragment in-register and consume immediately.
    // k-permutation k(quad,j)=kk*32+(j>>2)*16+quad*4+(j&3) applied identically
    // to the V^T A-fragment (two 8B LDS reads) and the P^T B-fragment, which
    // is exactly the lane's packed exp2(st) registers. Row-sum l via ones-row
    // MFMA (permutation-invariant) so l matches the bf16 P exactly.
    __builtin_amdgcn_s_setprio(1);
    #pragma unroll
    for (int kk = 0; kk < 2; ++kk) {
        if (kk == 1 && !inc[2]) continue;
        U4V f;
        {
            Pack4 plo, phi;
            #pragma unroll
            for (int r = 0; r < 4; ++r)
                plo.b[r] = (bf16)exp2f(st[2 * kk][r] - mst);
            if (inc[2 * kk + 1]) {
                #pragma unroll
                for (int r = 0; r < 4; ++r)
                    phi.b[r] = (bf16)exp2f(st[2 * kk + 1][r] - mst);
            } else {
                phi.q.x = 0u; phi.q.y = 0u;
            }
            f.u.x = plo.q.x; f.u.y = plo.q.y;
            f.u.z = phi.q.x; f.u.w = phi.q.y;
        }
        const int c0 = kk * 4 + (quad >> 1);
        const int co = (quad & 1) << 2;
        #pragma unroll
        for (int dt = 0; dt < 4; ++dt) {
            const bf16* vrow = V_ + (size_t)(dt * 16 + col) * 64;
            uint2 va = *(const uint2*)(vrow + ((c0 ^ (col & 7)) << 3) + co);
            uint2 vb = *(const uint2*)(vrow + (((c0 + 2) ^ (col & 7)) << 3) + co);
            U4V vv;
            vv.u.x = va.x; vv.u.y = va.y; vv.u.z = vb.x; vv.u.w = vb.y;
            o[dt] = __builtin_amdgcn_mfma_f32_16x16x32_bf16(
                vv.v, f.v, o[dt], 0, 0, 0);
        }
        o4 = __builtin_amdgcn_mfma_f32_16x16x32_bf16(vf4, f.v, o4, 0, 0, 0);
    }
    __builtin_amdgcn_s_setprio(0);
}

__device__ __forceinline__ void tile_epilogue(
    bf16* __restrict__ Aout, int b, int h, int wq0,
    const f32x4 o[4], const f32x4& o4)
{
    const int lane = threadIdx.x & 63;
    const int quad = lane >> 4, col = lane & 15;
    // row-sum l(q) lives in o4[0] of lane (quad=0, col=q) -> broadcast
    float l = __shfl(o4[0], col);
    const float inv = 1.f / fmaxf(l, 1e-30f);
    const int qg = wq0 + col;
    #pragma unroll
    for (int dt = 0; dt < 4; ++dt) {
        Pack4 pk;
        #pragma unroll
        for (int r = 0; r < 4; ++r) pk.b[r] = (bf16)(o[dt][r] * inv);
        *(uint2*)(Aout + ((size_t)b * S_ + qg) * D_ + h * HD_
                  + dt * 16 + quad * 4) = pk.q;
    }
}

// ---------------- flash attention (causal) --------------------------------
// grid: (16, B*H). Block i runs q-tiles (31-i) [L] and (i) [S] SEQUENTIALLY
// per staged K/V tile in ONE k-loop over double-buffered LDS (issue-early
// prefetch of tile t+1 before computing t; one __syncthreads per iter whose
// vmcnt(0) lands after compute has hidden the HBM latency).
__global__ __launch_bounds__(256, 4) void attn_k(
    const bf16* __restrict__ Q, const bf16* __restrict__ K,
    const bf16* __restrict__ VT, bf16* __restrict__ Aout)
{
    __shared__ __align__(16) bf16 lK[2][64 * 64];   // [k][d], chunk^=(k&7)
    __shared__ __align__(16) bf16 lV[2][64 * 64];   // [d][k], chunk^=(d&7)
    const int bh = blockIdx.y;
    const bf16* Qp = Q + (size_t)bh * S_ * HD_;
    const bf16* Kp = K + (size_t)bh * S_ * HD_;
    const bf16* Vp = VT + (size_t)bh * HD_ * S_;
    const int b = bh >> 4, h = bh & 15;
    const int t = threadIdx.x;
    const int lane = t & 63, w = t >> 6;
    const int quad = lane >> 4, col = lane & 15;

    const int q0L = (31 - (int)blockIdx.x) * 64;
    const int q0S = (int)blockIdx.x * 64;
    const int wq0L = q0L + w * 16, wq0S = q0S + w * 16;
    const int nt = 32 - (int)blockIdx.x;          // staged k-tiles

    // Q fragments (B-operand): B[n=q][k=d], n=col, k=quad*8+j
    bf16x8 qfL[2], qfS[2];
    #pragma unroll
    for (int cc = 0; cc < 2; ++cc) {
        qfL[cc] = *(const bf16x8*)(Qp + (size_t)(wq0L + col) * HD_
                                   + cc * 32 + quad * 8);
        qfS[cc] = *(const bf16x8*)(Qp + (size_t)(wq0S + col) * HD_
                                   + cc * 32 + quad * 8);
    }
    // ones-row A-fragment for the MFMA row-sum: A[m][k] = (m==0)
    const bf16 ov = (bf16)(col == 0 ? 1.0f : 0.0f);
    const bf16x8 vf4 = {ov, ov, ov, ov, ov, ov, ov, ov};

    f32x4 oL[4], oS[4], o4L, o4S;
    const f32x4 z = {0.f, 0.f, 0.f, 0.f};
    #pragma unroll
    for (int dt = 0; dt < 4; ++dt) { oL[dt] = z; oS[dt] = z; }
    o4L = z; o4S = z;
    float mstL = NEG_SENT, mstS = NEG_SENT;

    // ---- stage K[k0:+64][0:64] and V^T[0:64][k0:+64] into buffer bb ----
    auto stage = [&](int k0, int bb) {
        #pragma unroll
        for (int i = 0; i < 2; ++i) {
            int slot = t + i * 256;          // 0..511
            int rr = slot >> 3, ch = slot & 7;
            int sw = (ch ^ (rr & 7)) << 3;
            load16(Kp + (size_t)(k0 + rr) * HD_ + sw, &lK[bb][slot * 8]);
            load16(Vp + (size_t)rr * S_ + k0 + sw, &lV[bb][slot * 8]);
        }
    };

    stage(0, 0);
    __syncthreads();
    int cur = 0;

    for (int it = 0; it < nt; ++it) {
        const int k0 = it << 6;
        if (it + 1 < nt) stage(k0 + 64, cur ^ 1);   // issue-early prefetch
        const bf16* K_ = &lK[cur][0];
        const bf16* V_ = &lV[cur][0];
        tile_body(K_, V_, qfL, vf4, oL, o4L, mstL, k0, wq0L);
        if (k0 <= q0S)
            tile_body(K_, V_, qfS, vf4, oS, o4S, mstS, k0, wq0S);
        __syncthreads();   // drains prefetch vmcnt (hidden under compute)
        cur ^= 1;
    }

    tile_epilogue(Aout, b, h, wq0L, oL, o4L);
    tile_epilogue(Aout, b, h, wq0S, oS, o4S);
}

// ---------------- output projection (dtype-aware store) ----------------
__global__ __launch_bounds__(256) void gemm_out_k(
    const bf16* __restrict__ A, const bf16* __restrict__ WoT,
    const bf16* __restrict__ Bo, void* __restrict__ Out,
    const int* __restrict__ flag)
{
    __shared__ __align__(16) bf16 lA[128 * 32];
    __shared__ __align__(16) bf16 lB[128 * 32];
    f32x4 acc[4][4];
    const f32x4 z = {0.f, 0.f, 0.f, 0.f};
    #pragma unroll
    for (int i = 0; i < 4; ++i)
        #pragma unroll
        for (int j = 0; j < 4; ++j) acc[i][j] = z;
    const int m0 = blockIdx.x * 128, n0 = blockIdx.y * 128;
    gemm_core(A, WoT, lA, lB, acc, m0, n0);
    const int t = threadIdx.x, lane = t & 63, wave = t >> 6;
    const int wm = (wave >> 1) << 6, wn = (wave & 1) << 6;
    const int quad = lane >> 4, col = lane & 15;
    const int isb = *flag;
    #pragma unroll
    for (int mi = 0; mi < 4; ++mi) {
        int gm = m0 + wm + mi * 16 + quad * 4;
        #pragma unroll
        for (int ni = 0; ni < 4; ++ni) {
            int gn = n0 + wn + ni * 16 + col;
            float bb = (float)Bo[gn];
            #pragma unroll
            for (int r = 0; r < 4; ++r) {
                float v = acc[mi][ni][r] + bb;
                size_t off = (size_t)(gm + r) * D_ + gn;
                if (isb) ((bf16*)Out)[off] = (bf16)v;
                else     ((float*)Out)[off] = v;
            }
        }
    }
}

extern "C" void kernel_launch(void* const* d_in, const int* in_sizes, int n_in,
                              void* d_out, int out_size, void* d_ws, size_t ws_size,
                              hipStream_t stream)
{
    const void* x  = d_in[0];
    const void* wq = d_in[1];
    const void* bq = d_in[2];
    const void* wk = d_in[3];
    const void* bk = d_in[4];
    const void* wv = d_in[5];
    const void* bv = d_in[6];
    const void* wo = d_in[7];
    const void* bo = d_in[8];

    bf16* ws  = (bf16*)d_ws;
    bf16* XN  = ws + XN_OFF;                 // also reused as Ab
    bf16* WT  = ws + WT_OFF;
    bf16* BN  = ws + BN_OFF;
    int*  flag = (int*)((char*)d_ws + FLAG_BYTE);
    bf16* Qb  = ws + Q_OFF;
    bf16* Kb  = ws + K_OFF;
    bf16* VTb = ws + VT_OFF;
    bf16* Ab  = XN;

    hipLaunchKernelGGL(detect_k, dim3(1), dim3(256), 0, stream,
                       (const u16*)x, flag);
    hipLaunchKernelGGL(norm_x_k, dim3(8192), dim3(256), 0, stream,
                       x, XN, flag);
    hipLaunchKernelGGL(transpose_w, dim3(16, 16, 4), dim3(256), 0, stream,
                       wq, wk, wv, wo, WT, flag);
    hipLaunchKernelGGL(norm_b_k, dim3(4), dim3(256), 0, stream,
                       bq, bk, bv, bo, BN, flag);
    hipLaunchKernelGGL(gemm_qkv_k, dim3(64, 8, 3), dim3(256), 0, stream,
                       XN, WT, BN, Qb, Kb, VTb);
    hipLaunchKernelGGL(attn_k, dim3(16, 64), dim3(256), 0, stream,
                       Qb, Kb, VTb, Ab);
    hipLaunchKernelGGL(gemm_out_k, dim3(64, 8), dim3(256), 0, stream,
                       Ab, WT + ((size_t)3u << 20), BN + 3072, d_out, flag);
}

// Round 4
// 469.011 us; speedup vs baseline: 1.8419x; 1.2631x over previous
//
#include <hip/hip_runtime.h>
#include <hip/hip_bf16.h>

typedef __bf16 bf16;
typedef bf16 bf16x8 __attribute__((ext_vector_type(8)));
typedef float f32x4 __attribute__((ext_vector_type(4)));
typedef unsigned short u16;

#define B_ 4
#define S_ 2048
#define D_ 1024
#define H_ 16
#define HD_ 64

#define NEG_SENT -30000.0f

// workspace layout (bf16 element offsets)
#define XN_OFF   ((size_t)0)          // 8388608 elems; reused as Ab after QKV
#define WT_OFF   ((size_t)8388608)    // 4 x 1048576
#define BN_OFF   ((size_t)12582912)   // 4 x 1024
#define FLAG_BYTE ((size_t)25174016)  // int flag
#define Q_OFF    ((size_t)12587520)
#define K_OFF    ((size_t)20976128)
#define VT_OFF   ((size_t)29364736)

union Pack4 { bf16 b[4]; uint2 q; };
union U4V  { uint4 u; bf16x8 v; };

// XOR swizzle for 8-elem (16B) chunks in a [row][64] bf16 tile.
// row&7 breaks the row-major bank alias; row-bit3 term breaks the
// col vs col+8 collision of the PV 8B reads (4-way -> 2-way = free).
__device__ __forceinline__ int SWZ(int row, int c) {
    return (c ^ (row & 7) ^ (((row >> 3) & 1) << 1)) << 3;
}

__device__ __forceinline__ void load16(const bf16* g, bf16* l) {
    __builtin_amdgcn_global_load_lds(
        (const __attribute__((address_space(1))) void*)g,
        (__attribute__((address_space(3))) void*)l, 16, 0, 0);
}

// ---------------- dtype detection ----------------
__global__ __launch_bounds__(256) void detect_k(const u16* __restrict__ x,
                                                int* __restrict__ flag)
{
    __shared__ int cnt;
    if (threadIdx.x == 0) cnt = 0;
    __syncthreads();
    int c = 0;
    for (int i = threadIdx.x; i < 4096; i += 256) {
        u16 w = x[i * 2];            // even-indexed words
        int e = (w >> 7) & 0xFF;
        if (e >= 100 && e <= 135) c++;
    }
    atomicAdd(&cnt, c);
    __syncthreads();
    if (threadIdx.x == 0) *flag = (cnt > 2048) ? 1 : 0;   // 1 = bf16
}

// ---------------- input normalization: x -> bf16 XN ----------------
__global__ __launch_bounds__(256) void norm_x_k(const void* __restrict__ src,
                                                bf16* __restrict__ dst,
                                                const int* __restrict__ flag)
{
    const int qi = blockIdx.x * 256 + threadIdx.x;   // quad index, 4 elems each
    if (*flag) {
        ((uint2*)dst)[qi] = ((const uint2*)src)[qi];
    } else {
        float4 v = ((const float4*)src)[qi];
        Pack4 p;
        p.b[0] = (bf16)v.x; p.b[1] = (bf16)v.y;
        p.b[2] = (bf16)v.z; p.b[3] = (bf16)v.w;
        ((uint2*)dst)[qi] = p.q;
    }
}

// ---------------- bias normalization ----------------
__global__ __launch_bounds__(256) void norm_b_k(
    const void* __restrict__ b0, const void* __restrict__ b1,
    const void* __restrict__ b2, const void* __restrict__ b3,
    bf16* __restrict__ BN, const int* __restrict__ flag)
{
    const int mat = blockIdx.x;
    const void* src = (mat == 0) ? b0 : (mat == 1) ? b1 : (mat == 2) ? b2 : b3;
    bf16* dst = BN + mat * 1024;
    const int i = threadIdx.x * 4;
    if (*flag) {
        ((uint2*)(dst + i))[0] = *(const uint2*)((const bf16*)src + i);
    } else {
        const float* s = (const float*)src;
        Pack4 p;
        p.b[0] = (bf16)s[i + 0]; p.b[1] = (bf16)s[i + 1];
        p.b[2] = (bf16)s[i + 2]; p.b[3] = (bf16)s[i + 3];
        ((uint2*)(dst + i))[0] = p.q;
    }
}

// ---------- weight normalize + transpose: W[K][N] -> WT[N][K] (bf16) ----------
__global__ __launch_bounds__(256) void transpose_w(
    const void* __restrict__ W0, const void* __restrict__ W1,
    const void* __restrict__ W2, const void* __restrict__ W3,
    bf16* __restrict__ WT, const int* __restrict__ flag)
{
    __shared__ __align__(16) bf16 tile[64][65];
    const int mat = blockIdx.z;
    const void* W = (mat == 0) ? W0 : (mat == 1) ? W1 : (mat == 2) ? W2 : W3;
    bf16* O = WT + ((size_t)mat << 20);
    const int r0 = blockIdx.y * 64, c0 = blockIdx.x * 64;
    const int t = threadIdx.x;
    const int isb = *flag;
    #pragma unroll
    for (int i = 0; i < 16; ++i) {
        int idx = t + i * 256;
        int r = idx >> 6, c = idx & 63;
        size_t off = (size_t)(r0 + r) * D_ + c0 + c;
        tile[r][c] = isb ? ((const bf16*)W)[off] : (bf16)((const float*)W)[off];
    }
    __syncthreads();
    #pragma unroll
    for (int i = 0; i < 16; ++i) {
        int idx = t + i * 256;
        int rr = idx & 63, cc = idx >> 6;
        O[(size_t)(c0 + cc) * D_ + r0 + rr] = tile[rr][cc];
    }
}

// ---------------- shared 128x128 GEMM mainloop (m97 structure) ----------------
__device__ __forceinline__ void gemm_core(const bf16* __restrict__ A,
                                          const bf16* __restrict__ Bt,
                                          bf16* lA, bf16* lB,
                                          f32x4 acc[4][4], int m0, int n0)
{
    const int t = threadIdx.x;
    const int lane = t & 63;
    const int wave = t >> 6;
    const int wm = (wave >> 1) << 6;
    const int wn = (wave & 1) << 6;
    const int quad = lane >> 4;
    const int col = lane & 15;
    for (int k0 = 0; k0 < D_; k0 += 32) {
        #pragma unroll
        for (int i = 0; i < 2; ++i) {
            int slot = t + i * 256;
            int row = slot >> 2;
            int kc = (slot & 3) << 3;
            load16(A + (size_t)(m0 + row) * D_ + k0 + kc, lA + slot * 8);
            load16(Bt + (size_t)(n0 + row) * D_ + k0 + kc, lB + slot * 8);
        }
        __syncthreads();
        bf16x8 af[4], bfr[4];
        #pragma unroll
        for (int mi = 0; mi < 4; ++mi)
            af[mi] = *(const bf16x8*)(lA + (wm + mi * 16 + col) * 32 + quad * 8);
        #pragma unroll
        for (int ni = 0; ni < 4; ++ni)
            bfr[ni] = *(const bf16x8*)(lB + (wn + ni * 16 + col) * 32 + quad * 8);
        #pragma unroll
        for (int mi = 0; mi < 4; ++mi)
            #pragma unroll
            for (int ni = 0; ni < 4; ++ni)
                acc[mi][ni] = __builtin_amdgcn_mfma_f32_16x16x32_bf16(
                    af[mi], bfr[ni], acc[mi][ni], 0, 0, 0);
        __syncthreads();
    }
}

// ---------------- QKV projection ----------------
// mode 0: Q scaled by (1/8)*log2(e) -> [b][h][s][hd]; mode 1: K; mode 2: V^T
__global__ __launch_bounds__(256) void gemm_qkv_k(
    const bf16* __restrict__ X, const bf16* __restrict__ WT,
    const bf16* __restrict__ BN,
    bf16* __restrict__ Qo, bf16* __restrict__ Ko, bf16* __restrict__ Vo)
{
    __shared__ __align__(16) bf16 lA[128 * 32];
    __shared__ __align__(16) bf16 lB[128 * 32];
    const int mode = blockIdx.z;
    const bf16* Wsel = WT + ((size_t)mode << 20);
    const bf16* bias = BN + mode * 1024;
    f32x4 acc[4][4];
    const f32x4 z = {0.f, 0.f, 0.f, 0.f};
    #pragma unroll
    for (int i = 0; i < 4; ++i)
        #pragma unroll
        for (int j = 0; j < 4; ++j) acc[i][j] = z;
    const int m0 = blockIdx.x * 128, n0 = blockIdx.y * 128;
    gemm_core(X, Wsel, lA, lB, acc, m0, n0);
    const int t = threadIdx.x, lane = t & 63, wave = t >> 6;
    const int wm = (wave >> 1) << 6, wn = (wave & 1) << 6;
    const int quad = lane >> 4, col = lane & 15;
    // 0.125 * log2(e): softmax later uses raw exp2
    const float scale = (mode == 0) ? 0.18033688011112042f : 1.0f;
    #pragma unroll
    for (int mi = 0; mi < 4; ++mi) {
        int gm = m0 + wm + mi * 16 + quad * 4;
        int b = gm >> 11, srow = gm & 2047;
        #pragma unroll
        for (int ni = 0; ni < 4; ++ni) {
            int gn = n0 + wn + ni * 16 + col;
            float bb = (float)bias[gn];
            int h = gn >> 6, hd = gn & 63;
            if (mode == 2) {
                // V^T: 4 r-values are contiguous in s -> one 8B store
                Pack4 pk;
                #pragma unroll
                for (int r = 0; r < 4; ++r)
                    pk.b[r] = (bf16)(acc[mi][ni][r] + bb);
                *(uint2*)(Vo + (((size_t)b * H_ + h) * HD_ + hd) * S_ + srow)
                    = pk.q;
            } else {
                #pragma unroll
                for (int r = 0; r < 4; ++r) {
                    float v = (acc[mi][ni][r] + bb) * scale;
                    if (mode == 1)
                        Ko[(((size_t)b * H_ + h) * S_ + srow + r) * HD_ + hd] = (bf16)v;
                    else
                        Qo[(((size_t)b * H_ + h) * S_ + srow + r) * HD_ + hd] = (bf16)v;
                }
            }
        }
    }
}

// ---- one 64-k step: QK^T -> online softmax (deferred max) -> PV with
//      in-register P (permuted-k; no LDS round-trip). Math verified on HW
//      (R2/R3 absmax 0.0078).
__device__ __forceinline__ void tile_body(
    const bf16* __restrict__ K_, const bf16* __restrict__ V_,
    const bf16x8 qf[2], const bf16x8& vf4,
    f32x4 o[4], f32x4& o4, float& mst,
    int k0, int wq0)
{
    const int lane = threadIdx.x & 63;
    const int quad = lane >> 4, col = lane & 15;
    const f32x4 z = {0.f, 0.f, 0.f, 0.f};
    // wave-uniform tile inclusion (k-subtile mt needed iff its min k <= max q)
    bool inc[4];
    #pragma unroll
    for (int mt = 0; mt < 4; ++mt)
        inc[mt] = (k0 + mt * 16 <= wq0 + 15);

    // ---- S^T[mt=k] = K·Q^T ----
    f32x4 st[4];
    #pragma unroll
    for (int mt = 0; mt < 4; ++mt) st[mt] = z;
    __builtin_amdgcn_s_setprio(1);
    #pragma unroll
    for (int cc = 0; cc < 2; ++cc) {
        #pragma unroll
        for (int mt = 0; mt < 4; ++mt)
            if (inc[mt]) {
                bf16x8 af = *(const bf16x8*)(K_ + (mt * 16 + col) * 64
                            + SWZ(col, cc * 4 + quad));
                st[mt] = __builtin_amdgcn_mfma_f32_16x16x32_bf16(
                    af, qf[cc], st[mt], 0, 0, 0);
            }
    }
    __builtin_amdgcn_s_setprio(0);

    // ---- diagonal mask ----
    if (k0 + 64 > wq0) {
        #pragma unroll
        for (int mt = 0; mt < 4; ++mt)
            if (inc[mt]) {
                #pragma unroll
                for (int r = 0; r < 4; ++r)
                    if (k0 + mt * 16 + quad * 4 + r > wq0 + col)
                        st[mt][r] = NEG_SENT;
            }
    }

    // ---- online max per q (= col) ----
    float tm = fmaxf(fmaxf(st[0][0], st[0][1]), fmaxf(st[0][2], st[0][3]));
    #pragma unroll
    for (int mt = 1; mt < 4; ++mt)
        if (inc[mt])
            tm = fmaxf(tm, fmaxf(fmaxf(st[mt][0], st[mt][1]),
                                 fmaxf(st[mt][2], st[mt][3])));
    tm = fmaxf(tm, __shfl_xor(tm, 16));
    tm = fmaxf(tm, __shfl_xor(tm, 32));
    // deferred-max (T13): only rescale when max grew by > 8 (exp2 units);
    // P then bounded by 2^8 = 256 — bf16-safe.
    if (!__all(tm <= mst + 8.0f)) {
        float mn = fmaxf(mst, tm);
        float al = exp2f(mst - mn);
        #pragma unroll
        for (int dt = 0; dt < 4; ++dt) o[dt] *= al;
        o4 *= al;
        mst = mn;
    }

    // ---- PV: per kk build P fragment in-register and consume immediately.
    // k-permutation k(quad,j)=kk*32+(j>>2)*16+quad*4+(j&3) applied identically
    // to the V^T A-fragment (two 8B LDS reads) and the P^T B-fragment, which
    // is exactly the lane's packed exp2(st) registers. Row-sum l via ones-row
    // MFMA (permutation-invariant) so l matches the bf16 P exactly.
    __builtin_amdgcn_s_setprio(1);
    #pragma unroll
    for (int kk = 0; kk < 2; ++kk) {
        if (kk == 1 && !inc[2]) continue;
        U4V f;
        {
            Pack4 plo, phi;
            #pragma unroll
            for (int r = 0; r < 4; ++r)
                plo.b[r] = (bf16)exp2f(st[2 * kk][r] - mst);
            if (inc[2 * kk + 1]) {
                #pragma unroll
                for (int r = 0; r < 4; ++r)
                    phi.b[r] = (bf16)exp2f(st[2 * kk + 1][r] - mst);
            } else {
                phi.q.x = 0u; phi.q.y = 0u;
            }
            f.u.x = plo.q.x; f.u.y = plo.q.y;
            f.u.z = phi.q.x; f.u.w = phi.q.y;
        }
        const int c0 = kk * 4 + (quad >> 1);
        const int co = (quad & 1) << 2;
        #pragma unroll
        for (int dt = 0; dt < 4; ++dt) {
            const bf16* vrow = V_ + (size_t)(dt * 16 + col) * 64;
            uint2 va = *(const uint2*)(vrow + SWZ(col, c0) + co);
            uint2 vb = *(const uint2*)(vrow + SWZ(col, c0 + 2) + co);
            U4V vv;
            vv.u.x = va.x; vv.u.y = va.y; vv.u.z = vb.x; vv.u.w = vb.y;
            o[dt] = __builtin_amdgcn_mfma_f32_16x16x32_bf16(
                vv.v, f.v, o[dt], 0, 0, 0);
        }
        o4 = __builtin_amdgcn_mfma_f32_16x16x32_bf16(vf4, f.v, o4, 0, 0, 0);
    }
    __builtin_amdgcn_s_setprio(0);
}

__device__ __forceinline__ void tile_epilogue(
    bf16* __restrict__ Aout, int b, int h, int wq0,
    const f32x4 o[4], const f32x4& o4)
{
    const int lane = threadIdx.x & 63;
    const int quad = lane >> 4, col = lane & 15;
    // row-sum l(q) lives in o4[0] of lane (quad=0, col=q) -> broadcast
    float l = __shfl(o4[0], col);
    const float inv = 1.f / fmaxf(l, 1e-30f);
    const int qg = wq0 + col;
    #pragma unroll
    for (int dt = 0; dt < 4; ++dt) {
        Pack4 pk;
        #pragma unroll
        for (int r = 0; r < 4; ++r) pk.b[r] = (bf16)(o[dt][r] * inv);
        *(uint2*)(Aout + ((size_t)b * S_ + qg) * D_ + h * HD_
                  + dt * 16 + quad * 4) = pk.q;
    }
}

// ---------------- flash attention (causal) --------------------------------
// grid: (16, B*H). Block i runs q-tile (31-i) then q-tile (i) as two
// SEPARATE double-buffered k-loop passes — only ONE tile's state is live at
// a time (R2/R3 lesson: two-tile persistent state exceeds the 128-reg
// unified budget at 4 blocks/CU and spills to scratch). (32-i)+(i+1)=33
// staged iters per block -> uniform work. Per iter: issue-early prefetch of
// tile t+1, compute tile t (in-register P), one __syncthreads whose implicit
// vmcnt(0) lands after compute has hidden the HBM latency.
__global__ __launch_bounds__(256, 4) void attn_k(
    const bf16* __restrict__ Q, const bf16* __restrict__ K,
    const bf16* __restrict__ VT, bf16* __restrict__ Aout)
{
    __shared__ __align__(16) bf16 lK[2][64 * 64];   // [k][d], SWZ chunks
    __shared__ __align__(16) bf16 lV[2][64 * 64];   // [d][k], SWZ chunks
    const int bh = blockIdx.y;
    const bf16* Qp = Q + (size_t)bh * S_ * HD_;
    const bf16* Kp = K + (size_t)bh * S_ * HD_;
    const bf16* Vp = VT + (size_t)bh * HD_ * S_;
    const int b = bh >> 4, h = bh & 15;
    const int t = threadIdx.x;
    const int lane = t & 63, w = t >> 6;
    const int quad = lane >> 4, col = lane & 15;

    // ones-row A-fragment for the MFMA row-sum: A[m][k] = (m==0)
    const bf16 ov = (bf16)(col == 0 ? 1.0f : 0.0f);
    const bf16x8 vf4 = {ov, ov, ov, ov, ov, ov, ov, ov};
    const f32x4 z = {0.f, 0.f, 0.f, 0.f};

    // ---- stage K[k0:+64][0:64] and V^T[0:64][k0:+64] into buffer bb ----
    auto stage = [&](int k0, int bb) {
        #pragma unroll
        for (int i = 0; i < 2; ++i) {
            int slot = t + i * 256;          // 0..511
            int rr = slot >> 3, ch = slot & 7;
            int sw = SWZ(rr, ch);            // pre-swizzled global source
            load16(Kp + (size_t)(k0 + rr) * HD_ + sw, &lK[bb][slot * 8]);
            load16(Vp + (size_t)rr * S_ + k0 + sw, &lV[bb][slot * 8]);
        }
    };

    #pragma unroll
    for (int pass = 0; pass < 2; ++pass) {
        const int q0 = (pass == 0 ? (31 - (int)blockIdx.x) : (int)blockIdx.x)
                       * 64;
        const int wq0 = q0 + w * 16;
        const int nt = (q0 >> 6) + 1;        // staged k-tiles this pass

        // Q fragments (B-operand): B[n=q][k=d], n=col, k=quad*8+j
        bf16x8 qf[2];
        #pragma unroll
        for (int cc = 0; cc < 2; ++cc)
            qf[cc] = *(const bf16x8*)(Qp + (size_t)(wq0 + col) * HD_
                                      + cc * 32 + quad * 8);
        f32x4 o[4], o4;
        #pragma unroll
        for (int dt = 0; dt < 4; ++dt) o[dt] = z;
        o4 = z;
        float mst = NEG_SENT;

        stage(0, 0);
        __syncthreads();
        int cur = 0;
        for (int it = 0; it < nt; ++it) {
            const int k0 = it << 6;
            if (it + 1 < nt) stage(k0 + 64, cur ^ 1);   // issue-early prefetch
            tile_body(&lK[cur][0], &lV[cur][0], qf, vf4, o, o4, mst, k0, wq0);
            __syncthreads();   // drains prefetch vmcnt (hidden under compute)
            cur ^= 1;
        }
        tile_epilogue(Aout, b, h, wq0, o, o4);
        // loop's final __syncthreads orders LDS reuse across passes;
        // epilogue touches only global memory.
    }
}

// ---------------- output projection (dtype-aware store) ----------------
__global__ __launch_bounds__(256) void gemm_out_k(
    const bf16* __restrict__ A, const bf16* __restrict__ WoT,
    const bf16* __restrict__ Bo, void* __restrict__ Out,
    const int* __restrict__ flag)
{
    __shared__ __align__(16) bf16 lA[128 * 32];
    __shared__ __align__(16) bf16 lB[128 * 32];
    f32x4 acc[4][4];
    const f32x4 z = {0.f, 0.f, 0.f, 0.f};
    #pragma unroll
    for (int i = 0; i < 4; ++i)
        #pragma unroll
        for (int j = 0; j < 4; ++j) acc[i][j] = z;
    const int m0 = blockIdx.x * 128, n0 = blockIdx.y * 128;
    gemm_core(A, WoT, lA, lB, acc, m0, n0);
    const int t = threadIdx.x, lane = t & 63, wave = t >> 6;
    const int wm = (wave >> 1) << 6, wn = (wave & 1) << 6;
    const int quad = lane >> 4, col = lane & 15;
    const int isb = *flag;
    #pragma unroll
    for (int mi = 0; mi < 4; ++mi) {
        int gm = m0 + wm + mi * 16 + quad * 4;
        #pragma unroll
        for (int ni = 0; ni < 4; ++ni) {
            int gn = n0 + wn + ni * 16 + col;
            float bb = (float)Bo[gn];
            #pragma unroll
            for (int r = 0; r < 4; ++r) {
                float v = acc[mi][ni][r] + bb;
                size_t off = (size_t)(gm + r) * D_ + gn;
                if (isb) ((bf16*)Out)[off] = (bf16)v;
                else     ((float*)Out)[off] = v;
            }
        }
    }
}

extern "C" void kernel_launch(void* const* d_in, const int* in_sizes, int n_in,
                              void* d_out, int out_size, void* d_ws, size_t ws_size,
                              hipStream_t stream)
{
    const void* x  = d_in[0];
    const void* wq = d_in[1];
    const void* bq = d_in[2];
    const void* wk = d_in[3];
    const void* bk = d_in[4];
    const void* wv = d_in[5];
    const void* bv = d_in[6];
    const void* wo = d_in[7];
    const void* bo = d_in[8];

    bf16* ws  = (bf16*)d_ws;
    bf16* XN  = ws + XN_OFF;                 // also reused as Ab
    bf16* WT  = ws + WT_OFF;
    bf16* BN  = ws + BN_OFF;
    int*  flag = (int*)((char*)d_ws + FLAG_BYTE);
    bf16* Qb  = ws + Q_OFF;
    bf16* Kb  = ws + K_OFF;
    bf16* VTb = ws + VT_OFF;
    bf16* Ab  = XN;

    hipLaunchKernelGGL(detect_k, dim3(1), dim3(256), 0, stream,
                       (const u16*)x, flag);
    hipLaunchKernelGGL(norm_x_k, dim3(8192), dim3(256), 0, stream,
                       x, XN, flag);
    hipLaunchKernelGGL(transpose_w, dim3(16, 16, 4), dim3(256), 0, stream,
                       wq, wk, wv, wo, WT, flag);
    hipLaunchKernelGGL(norm_b_k, dim3(4), dim3(256), 0, stream,
                       bq, bk, bv, bo, BN, flag);
    hipLaunchKernelGGL(gemm_qkv_k, dim3(64, 8, 3), dim3(256), 0, stream,
                       XN, WT, BN, Qb, Kb, VTb);
    hipLaunchKernelGGL(attn_k, dim3(16, 64), dim3(256), 0, stream,
                       Qb, Kb, VTb, Ab);
    hipLaunchKernelGGL(gemm_out_k, dim3(64, 8), dim3(256), 0, stream,
                       Ab, WT + ((size_t)3u << 20), BN + 3072, d_out, flag);
}

// Round 5
// 288.276 us; speedup vs baseline: 2.9967x; 1.6269x over previous
//
#include <hip/hip_runtime.h>
#include <hip/hip_bf16.h>

typedef __bf16 bf16;
typedef bf16 bf16x8 __attribute__((ext_vector_type(8)));
typedef float f32x4 __attribute__((ext_vector_type(4)));
typedef unsigned short u16;

#define B_ 4
#define S_ 2048
#define D_ 1024
#define H_ 16
#define HD_ 64

#define NEG_SENT -30000.0f

// workspace layout (bf16 element offsets)
#define XN_OFF   ((size_t)0)          // 8388608 elems; reused as Ab after QKV
#define WT_OFF   ((size_t)8388608)    // 4 x 1048576
#define BN_OFF   ((size_t)12582912)   // 4 x 1024
#define FLAG_BYTE ((size_t)25174016)  // int flag
#define Q_OFF    ((size_t)12587520)
#define K_OFF    ((size_t)20976128)
#define VT_OFF   ((size_t)29364736)

union Pack4 { bf16 b[4]; uint2 q; };

__device__ __forceinline__ void load16(const bf16* g, bf16* l) {
    __builtin_amdgcn_global_load_lds(
        (const __attribute__((address_space(1))) void*)g,
        (__attribute__((address_space(3))) void*)l, 16, 0, 0);
}

// ---------------- dtype detection ----------------
__global__ __launch_bounds__(256) void detect_k(const u16* __restrict__ x,
                                                int* __restrict__ flag)
{
    __shared__ int cnt;
    if (threadIdx.x == 0) cnt = 0;
    __syncthreads();
    int c = 0;
    for (int i = threadIdx.x; i < 4096; i += 256) {
        u16 w = x[i * 2];            // even-indexed words
        int e = (w >> 7) & 0xFF;
        if (e >= 100 && e <= 135) c++;
    }
    atomicAdd(&cnt, c);
    __syncthreads();
    if (threadIdx.x == 0) *flag = (cnt > 2048) ? 1 : 0;   // 1 = bf16
}

// ---------------- input normalization: x -> bf16 XN ----------------
__global__ __launch_bounds__(256) void norm_x_k(const void* __restrict__ src,
                                                bf16* __restrict__ dst,
                                                const int* __restrict__ flag)
{
    const int qi = blockIdx.x * 256 + threadIdx.x;   // quad index, 4 elems each
    if (*flag) {
        ((uint2*)dst)[qi] = ((const uint2*)src)[qi];
    } else {
        float4 v = ((const float4*)src)[qi];
        Pack4 p;
        p.b[0] = (bf16)v.x; p.b[1] = (bf16)v.y;
        p.b[2] = (bf16)v.z; p.b[3] = (bf16)v.w;
        ((uint2*)dst)[qi] = p.q;
    }
}

// ---------------- bias normalization ----------------
__global__ __launch_bounds__(256) void norm_b_k(
    const void* __restrict__ b0, const void* __restrict__ b1,
    const void* __restrict__ b2, const void* __restrict__ b3,
    bf16* __restrict__ BN, const int* __restrict__ flag)
{
    const int mat = blockIdx.x;
    const void* src = (mat == 0) ? b0 : (mat == 1) ? b1 : (mat == 2) ? b2 : b3;
    bf16* dst = BN + mat * 1024;
    const int i = threadIdx.x * 4;
    if (*flag) {
        ((uint2*)(dst + i))[0] = *(const uint2*)((const bf16*)src + i);
    } else {
        const float* s = (const float*)src;
        Pack4 p;
        p.b[0] = (bf16)s[i + 0]; p.b[1] = (bf16)s[i + 1];
        p.b[2] = (bf16)s[i + 2]; p.b[3] = (bf16)s[i + 3];
        ((uint2*)(dst + i))[0] = p.q;
    }
}

// ---------- weight normalize + transpose: W[K][N] -> WT[N][K] (bf16) ----------
__global__ __launch_bounds__(256) void transpose_w(
    const void* __restrict__ W0, const void* __restrict__ W1,
    const void* __restrict__ W2, const void* __restrict__ W3,
    bf16* __restrict__ WT, const int* __restrict__ flag)
{
    __shared__ __align__(16) bf16 tile[64][65];
    const int mat = blockIdx.z;
    const void* W = (mat == 0) ? W0 : (mat == 1) ? W1 : (mat == 2) ? W2 : W3;
    bf16* O = WT + ((size_t)mat << 20);
    const int r0 = blockIdx.y * 64, c0 = blockIdx.x * 64;
    const int t = threadIdx.x;
    const int isb = *flag;
    #pragma unroll
    for (int i = 0; i < 16; ++i) {
        int idx = t + i * 256;
        int r = idx >> 6, c = idx & 63;
        size_t off = (size_t)(r0 + r) * D_ + c0 + c;
        tile[r][c] = isb ? ((const bf16*)W)[off] : (bf16)((const float*)W)[off];
    }
    __syncthreads();
    #pragma unroll
    for (int i = 0; i < 16; ++i) {
        int idx = t + i * 256;
        int rr = idx & 63, cc = idx >> 6;
        O[(size_t)(c0 + cc) * D_ + r0 + rr] = tile[rr][cc];
    }
}

// ---------------- shared 128x128 GEMM mainloop (m97 structure) ----------------
__device__ __forceinline__ void gemm_core(const bf16* __restrict__ A,
                                          const bf16* __restrict__ Bt,
                                          bf16* lA, bf16* lB,
                                          f32x4 acc[4][4], int m0, int n0)
{
    const int t = threadIdx.x;
    const int lane = t & 63;
    const int wave = t >> 6;
    const int wm = (wave >> 1) << 6;
    const int wn = (wave & 1) << 6;
    const int quad = lane >> 4;
    const int col = lane & 15;
    for (int k0 = 0; k0 < D_; k0 += 32) {
        #pragma unroll
        for (int i = 0; i < 2; ++i) {
            int slot = t + i * 256;
            int row = slot >> 2;
            int kc = (slot & 3) << 3;
            load16(A + (size_t)(m0 + row) * D_ + k0 + kc, lA + slot * 8);
            load16(Bt + (size_t)(n0 + row) * D_ + k0 + kc, lB + slot * 8);
        }
        __syncthreads();
        bf16x8 af[4], bfr[4];
        #pragma unroll
        for (int mi = 0; mi < 4; ++mi)
            af[mi] = *(const bf16x8*)(lA + (wm + mi * 16 + col) * 32 + quad * 8);
        #pragma unroll
        for (int ni = 0; ni < 4; ++ni)
            bfr[ni] = *(const bf16x8*)(lB + (wn + ni * 16 + col) * 32 + quad * 8);
        #pragma unroll
        for (int mi = 0; mi < 4; ++mi)
            #pragma unroll
            for (int ni = 0; ni < 4; ++ni)
                acc[mi][ni] = __builtin_amdgcn_mfma_f32_16x16x32_bf16(
                    af[mi], bfr[ni], acc[mi][ni], 0, 0, 0);
        __syncthreads();
    }
}

// ---------------- QKV projection ----------------
// mode 0: Q scaled by (1/8)*log2(e) -> [b][h][s][hd]; mode 1: K; mode 2: V^T
__global__ __launch_bounds__(256) void gemm_qkv_k(
    const bf16* __restrict__ X, const bf16* __restrict__ WT,
    const bf16* __restrict__ BN,
    bf16* __restrict__ Qo, bf16* __restrict__ Ko, bf16* __restrict__ Vo)
{
    __shared__ __align__(16) bf16 lA[128 * 32];
    __shared__ __align__(16) bf16 lB[128 * 32];
    const int mode = blockIdx.z;
    const bf16* Wsel = WT + ((size_t)mode << 20);
    const bf16* bias = BN + mode * 1024;
    f32x4 acc[4][4];
    const f32x4 z = {0.f, 0.f, 0.f, 0.f};
    #pragma unroll
    for (int i = 0; i < 4; ++i)
        #pragma unroll
        for (int j = 0; j < 4; ++j) acc[i][j] = z;
    const int m0 = blockIdx.x * 128, n0 = blockIdx.y * 128;
    gemm_core(X, Wsel, lA, lB, acc, m0, n0);
    const int t = threadIdx.x, lane = t & 63, wave = t >> 6;
    const int wm = (wave >> 1) << 6, wn = (wave & 1) << 6;
    const int quad = lane >> 4, col = lane & 15;
    // 0.125 * log2(e): softmax later uses raw exp2
    const float scale = (mode == 0) ? 0.18033688011112042f : 1.0f;
    #pragma unroll
    for (int mi = 0; mi < 4; ++mi) {
        int gm = m0 + wm + mi * 16 + quad * 4;
        int b = gm >> 11, srow = gm & 2047;
        #pragma unroll
        for (int ni = 0; ni < 4; ++ni) {
            int gn = n0 + wn + ni * 16 + col;
            float bb = (float)bias[gn];
            int h = gn >> 6, hd = gn & 63;
            if (mode == 2) {
                // V^T: 4 r-values are contiguous in s -> one 8B store
                Pack4 pk;
                #pragma unroll
                for (int r = 0; r < 4; ++r)
                    pk.b[r] = (bf16)(acc[mi][ni][r] + bb);
                *(uint2*)(Vo + (((size_t)b * H_ + h) * HD_ + hd) * S_ + srow)
                    = pk.q;
            } else {
                #pragma unroll
                for (int r = 0; r < 4; ++r) {
                    float v = (acc[mi][ni][r] + bb) * scale;
                    if (mode == 1)
                        Ko[(((size_t)b * H_ + h) * S_ + srow + r) * HD_ + hd] = (bf16)v;
                    else
                        Qo[(((size_t)b * H_ + h) * S_ + srow + r) * HD_ + hd] = (bf16)v;
                }
            }
        }
    }
}

// ---- one 64-k step of one q-tile (proven R1 body: LDS-P keeps the arch-VGPR
//      peak under the 64-reg arch-side budget — R2/R3/R4 lesson: in-register
//      P spills to scratch at 4 blocks/CU) ----------------------------------
__device__ __forceinline__ void tile_step(
    const bf16* __restrict__ lK, const bf16* __restrict__ lV,
    bf16* __restrict__ lPTw,
    const bf16x8 qf[2], const bf16x8 vf4,
    f32x4 o[4], f32x4& o4, float& mst,
    int k0, int wq0)
{
    const int lane = threadIdx.x & 63;
    const int quad = lane >> 4, col = lane & 15;
    const f32x4 z = {0.f, 0.f, 0.f, 0.f};
    // wave-uniform tile inclusion (k-subtile mt needed iff its min k <= max q)
    bool inc[4];
    inc[0] = true;
    inc[1] = (k0 + 16 <= wq0 + 15);
    inc[2] = (k0 + 32 <= wq0 + 15);
    inc[3] = (k0 + 48 <= wq0 + 15);
    // S^T[mt=k] = K·Q^T
    f32x4 st[4];
    #pragma unroll
    for (int mt = 0; mt < 4; ++mt) st[mt] = z;
    __builtin_amdgcn_s_setprio(1);
    #pragma unroll
    for (int cc = 0; cc < 2; ++cc) {
        #pragma unroll
        for (int mt = 0; mt < 4; ++mt)
            if (inc[mt]) {
                bf16x8 af = *(const bf16x8*)(lK + (mt * 16 + col) * 64
                            + (((cc * 4 + quad) ^ (col & 7)) << 3));
                st[mt] = __builtin_amdgcn_mfma_f32_16x16x32_bf16(
                    af, qf[cc], st[mt], 0, 0, 0);
            }
    }
    __builtin_amdgcn_s_setprio(0);
    if (k0 + 64 > wq0) { // diagonal region: mask k > q
        #pragma unroll
        for (int mt = 0; mt < 4; ++mt)
            if (inc[mt]) {
                #pragma unroll
                for (int r = 0; r < 4; ++r)
                    if (k0 + mt * 16 + quad * 4 + r > wq0 + col)
                        st[mt][r] = NEG_SENT;
            }
    }
    // online max per q (= col): in-lane tree + 2 shuffles
    float tm = fmaxf(fmaxf(st[0][0], st[0][1]), fmaxf(st[0][2], st[0][3]));
    #pragma unroll
    for (int mt = 1; mt < 4; ++mt)
        if (inc[mt])
            tm = fmaxf(tm, fmaxf(fmaxf(st[mt][0], st[mt][1]),
                                 fmaxf(st[mt][2], st[mt][3])));
    tm = fmaxf(tm, __shfl_xor(tm, 16));
    tm = fmaxf(tm, __shfl_xor(tm, 32));
    // deferred-max (T13): only rescale when max grew by > 8 (exp2 units);
    // P then bounded by 2^8 = 256 — bf16-safe.
    if (!__all(tm <= mst + 8.0f)) {
        float mn = fmaxf(mst, tm);
        float al = exp2f(mst - mn);
        #pragma unroll
        for (int dt = 0; dt < 4; ++dt) o[dt] *= al;
        o4 *= al;
        mst = mn;
    }
    // P^T -> lPTw as [q][k]; zero-fill excluded tile a live PV read uses.
    // Row-sum comes from the ones-fragment MFMA below, so it sees exactly
    // the bf16 P (incl. zero-fills) that the numerator sees.
    #pragma unroll
    for (int mt = 0; mt < 4; ++mt) {
        int kch = mt * 2 + (quad >> 1);
        uint2* dst = (uint2*)(&lPTw[col * 64 + ((kch ^ (col & 7)) << 3)
                                    + ((quad & 1) << 2)]);
        if (inc[mt]) {
            Pack4 pk;
            #pragma unroll
            for (int r = 0; r < 4; ++r)
                pk.b[r] = (bf16)exp2f(st[mt][r] - mst);
            *dst = pk.q;
        } else if (mt == 1 || (mt == 3 && inc[2])) {
            uint2 zz; zz.x = 0u; zz.y = 0u;
            *dst = zz;
        }
    }
    // drain P writes before same-wave cross-lane reads (lgkm only: does NOT
    // stall on the in-flight global_load_lds prefetch, which is vmcnt)
    asm volatile("s_waitcnt lgkmcnt(0)" ::: "memory");
    // O^T += V^T · P^T ; l += ones · P^T
    __builtin_amdgcn_s_setprio(1);
    #pragma unroll
    for (int kk = 0; kk < 2; ++kk) {
        if (kk == 1 && !inc[2]) continue;
        bf16x8 pf = *(const bf16x8*)(&lPTw[col * 64
                    + (((kk * 4 + quad) ^ (col & 7)) << 3)]);
        #pragma unroll
        for (int dt = 0; dt < 4; ++dt) {
            bf16x8 vf = *(const bf16x8*)(lV + (dt * 16 + col) * 64
                        + (((kk * 4 + quad) ^ (col & 7)) << 3));
            o[dt] = __builtin_amdgcn_mfma_f32_16x16x32_bf16(
                vf, pf, o[dt], 0, 0, 0);
        }
        o4 = __builtin_amdgcn_mfma_f32_16x16x32_bf16(vf4, pf, o4, 0, 0, 0);
    }
    __builtin_amdgcn_s_setprio(0);
}

__device__ __forceinline__ void tile_epilogue(
    bf16* __restrict__ Aout, int b, int h, int wq0,
    const f32x4 o[4], const f32x4& o4)
{
    const int lane = threadIdx.x & 63;
    const int quad = lane >> 4, col = lane & 15;
    // row-sum l(q) lives in o4[0] of lane (quad=0, col=q) -> broadcast
    float l = __shfl(o4[0], col);
    const float inv = 1.f / fmaxf(l, 1e-30f);
    const int qg = wq0 + col;
    #pragma unroll
    for (int dt = 0; dt < 4; ++dt) {
        Pack4 pk;
        #pragma unroll
        for (int r = 0; r < 4; ++r) pk.b[r] = (bf16)(o[dt][r] * inv);
        *(uint2*)(Aout + ((size_t)b * S_ + qg) * D_ + h * HD_
                  + dt * 16 + quad * 4) = pk.q;
    }
}

// ---------------- flash attention (causal), merged paired q-tiles -----------
// grid: (16, B*H). Block i runs q-tiles (31-i) [L] and (i) [S] in ONE k-loop
// sharing each staged K/V tile (32-i staged iters; compute stays 33 steps ->
// uniform per-CU work). NEW vs R1: double-buffered K/V with issue-early
// prefetch (stage t+1 into alt buffer BEFORE computing t) and a single
// __syncthreads per iteration — its implicit vmcnt(0) lands after ~4000 cyc
// of compute has hidden the HBM latency, removing R1's serial ~900-cyc
// stage->barrier stall and one of the two barriers.
// LDS: 16K (lK dbuf) + 16K (lV dbuf) + 8K (lPT, shared by the sequential
// L/S bodies — same-wave LDS ordering covers the WAR) = 40 KB -> 4 blocks/CU.
__global__ __launch_bounds__(256, 4) void attn_k(
    const bf16* __restrict__ Q, const bf16* __restrict__ K,
    const bf16* __restrict__ VT, bf16* __restrict__ Aout)
{
    __shared__ __align__(16) bf16 lK[2][64 * 64];   // [k][d], chunk^=(k&7)
    __shared__ __align__(16) bf16 lV[2][64 * 64];   // [d][k], chunk^=(d&7)
    __shared__ __align__(16) bf16 lPT[4][16 * 64];  // per-wave [q][k], ^=(q&7)
    const int bh = blockIdx.y;
    const bf16* Qp = Q + (size_t)bh * S_ * HD_;
    const bf16* Kp = K + (size_t)bh * S_ * HD_;
    const bf16* Vp = VT + (size_t)bh * HD_ * S_;
    const int b = bh >> 4, h = bh & 15;
    const int t = threadIdx.x;
    const int lane = t & 63, w = t >> 6;
    const int quad = lane >> 4, col = lane & 15;
    bf16* lPTw = &lPT[w][0];

    const int q0L = (31 - (int)blockIdx.x) * 64;
    const int q0S = (int)blockIdx.x * 64;
    const int wq0L = q0L + w * 16, wq0S = q0S + w * 16;
    const int nt = 32 - (int)blockIdx.x;          // staged k-tiles

    // Q fragments (B-operand): B[n=q][k=d], n=col, k=quad*8+j
    bf16x8 qfL[2], qfS[2];
    #pragma unroll
    for (int cc = 0; cc < 2; ++cc) {
        qfL[cc] = *(const bf16x8*)(Qp + (size_t)(wq0L + col) * HD_
                                   + cc * 32 + quad * 8);
        qfS[cc] = *(const bf16x8*)(Qp + (size_t)(wq0S + col) * HD_
                                   + cc * 32 + quad * 8);
    }
    // ones-row A-fragment for the MFMA row-sum: A[m][k] = (m==0)
    const bf16 ov = (bf16)(col == 0 ? 1.0f : 0.0f);
    const bf16x8 vf4 = {ov, ov, ov, ov, ov, ov, ov, ov};

    f32x4 oL[4], oS[4], o4L, o4S;
    const f32x4 z = {0.f, 0.f, 0.f, 0.f};
    #pragma unroll
    for (int dt = 0; dt < 4; ++dt) { oL[dt] = z; oS[dt] = z; }
    o4L = z; o4S = z;
    float mstL = NEG_SENT, mstS = NEG_SENT;

    // ---- stage K[k0:+64][0:64] and V^T[0:64][k0:+64] into buffer bb ----
    auto stage = [&](int k0, int bb) {
        #pragma unroll
        for (int i = 0; i < 2; ++i) {
            int slot = t + i * 256;          // 0..511
            int rr = slot >> 3, ch = slot & 7;
            int sw = (ch ^ (rr & 7)) << 3;   // pre-swizzled global source
            load16(Kp + (size_t)(k0 + rr) * HD_ + sw, &lK[bb][slot * 8]);
            load16(Vp + (size_t)rr * S_ + k0 + sw, &lV[bb][slot * 8]);
        }
    };

    stage(0, 0);
    __syncthreads();
    int cur = 0;

    for (int it = 0; it < nt; ++it) {
        const int k0 = it << 6;
        if (it + 1 < nt) stage(k0 + 64, cur ^ 1);   // issue-early prefetch
        tile_step(&lK[cur][0], &lV[cur][0], lPTw, qfL, vf4,
                  oL, o4L, mstL, k0, wq0L);
        if (k0 <= q0S)
            tile_step(&lK[cur][0], &lV[cur][0], lPTw, qfS, vf4,
                      oS, o4S, mstS, k0, wq0S);
        __syncthreads();   // drains prefetch vmcnt (hidden under compute)
        cur ^= 1;
    }

    tile_epilogue(Aout, b, h, wq0L, oL, o4L);
    tile_epilogue(Aout, b, h, wq0S, oS, o4S);
}

// ---------------- output projection (dtype-aware store) ----------------
__global__ __launch_bounds__(256) void gemm_out_k(
    const bf16* __restrict__ A, const bf16* __restrict__ WoT,
    const bf16* __restrict__ Bo, void* __restrict__ Out,
    const int* __restrict__ flag)
{
    __shared__ __align__(16) bf16 lA[128 * 32];
    __shared__ __align__(16) bf16 lB[128 * 32];
    f32x4 acc[4][4];
    const f32x4 z = {0.f, 0.f, 0.f, 0.f};
    #pragma unroll
    for (int i = 0; i < 4; ++i)
        #pragma unroll
        for (int j = 0; j < 4; ++j) acc[i][j] = z;
    const int m0 = blockIdx.x * 128, n0 = blockIdx.y * 128;
    gemm_core(A, WoT, lA, lB, acc, m0, n0);
    const int t = threadIdx.x, lane = t & 63, wave = t >> 6;
    const int wm = (wave >> 1) << 6, wn = (wave & 1) << 6;
    const int quad = lane >> 4, col = lane & 15;
    const int isb = *flag;
    #pragma unroll
    for (int mi = 0; mi < 4; ++mi) {
        int gm = m0 + wm + mi * 16 + quad * 4;
        #pragma unroll
        for (int ni = 0; ni < 4; ++ni) {
            int gn = n0 + wn + ni * 16 + col;
            float bb = (float)Bo[gn];
            #pragma unroll
            for (int r = 0; r < 4; ++r) {
                float v = acc[mi][ni][r] + bb;
                size_t off = (size_t)(gm + r) * D_ + gn;
                if (isb) ((bf16*)Out)[off] = (bf16)v;
                else     ((float*)Out)[off] = v;
            }
        }
    }
}

extern "C" void kernel_launch(void* const* d_in, const int* in_sizes, int n_in,
                              void* d_out, int out_size, void* d_ws, size_t ws_size,
                              hipStream_t stream)
{
    const void* x  = d_in[0];
    const void* wq = d_in[1];
    const void* bq = d_in[2];
    const void* wk = d_in[3];
    const void* bk = d_in[4];
    const void* wv = d_in[5];
    const void* bv = d_in[6];
    const void* wo = d_in[7];
    const void* bo = d_in[8];

    bf16* ws  = (bf16*)d_ws;
    bf16* XN  = ws + XN_OFF;                 // also reused as Ab
    bf16* WT  = ws + WT_OFF;
    bf16* BN  = ws + BN_OFF;
    int*  flag = (int*)((char*)d_ws + FLAG_BYTE);
    bf16* Qb  = ws + Q_OFF;
    bf16* Kb  = ws + K_OFF;
    bf16* VTb = ws + VT_OFF;
    bf16* Ab  = XN;

    hipLaunchKernelGGL(detect_k, dim3(1), dim3(256), 0, stream,
                       (const u16*)x, flag);
    hipLaunchKernelGGL(norm_x_k, dim3(8192), dim3(256), 0, stream,
                       x, XN, flag);
    hipLaunchKernelGGL(transpose_w, dim3(16, 16, 4), dim3(256), 0, stream,
                       wq, wk, wv, wo, WT, flag);
    hipLaunchKernelGGL(norm_b_k, dim3(4), dim3(256), 0, stream,
                       bq, bk, bv, bo, BN, flag);
    hipLaunchKernelGGL(gemm_qkv_k, dim3(64, 8, 3), dim3(256), 0, stream,
                       XN, WT, BN, Qb, Kb, VTb);
    hipLaunchKernelGGL(attn_k, dim3(16, 64), dim3(256), 0, stream,
                       Qb, Kb, VTb, Ab);
    hipLaunchKernelGGL(gemm_out_k, dim3(64, 8), dim3(256), 0, stream,
                       Ab, WT + ((size_t)3u << 20), BN + 3072, d_out, flag);
}